// Round 3
// baseline (159.908 us; speedup 1.0000x reference)
//
#include <hip/hip_runtime.h>

// HashLoss: contrastive (logsumexp over ln@ln^T/0.2) + 0.5*MSE(H@H^T/128, Tn@Tn^T)
//         + 0.01*mean||logits|-1|
// B=4096. R15: occupancy experiment. R13 (3 blk/CU)=44.6us vs R14 (2 blk/CU)=43.6us
// was occupancy-insensitive at <=3 blk/CU; the 2-deep dbuf was useless (syncthreads
// drains vmcnt(0) anyway) yet cost 32KB LDS. Revert to 32KB single-buffer,
// __launch_bounds__(256,4) -> 4 blk/CU (16 waves/CU, untested quadrant).
// Mask RTT now hidden: issue mask global_load_lds into the freed slab AFTER last
// MFMA, run the exp-sum+shfl-reduce pass (~1000cy VALU) before the draining
// barrier, then a 2nd pass does the sparse mask atomics (sim kept in acc, scaled
// in place - no VGPR growth). G-role: single-buffer 8-chunk loop, private Cpart
// stores (no atomics). If mega stays ~43us this round, conclude harness-floor
// and pivot to dispatch fusion. 4 dispatches.

typedef __bf16 bf16x8 __attribute__((ext_vector_type(8)));
typedef float f32x4 __attribute__((ext_vector_type(4)));

__device__ __forceinline__ unsigned short f2bf(float f) {
  union { float f; unsigned int u; } v; v.f = f;
  unsigned int u = v.u;
  return (unsigned short)((u + 0x7FFFu + ((u >> 16) & 1u)) >> 16);  // RNE
}

__device__ __forceinline__ void atomAddF(float* p, float v) {
  unsafeAtomicAdd(p, v);  // HW f32 fadd (fire-and-forget), not CAS loop
}

// ---- prep: 256 blocks x 256 threads, 16 rows each. (unchanged from R14)
__global__ __launch_bounds__(256) void prep(const float* __restrict__ logits,
                                            const float* __restrict__ hash,
                                            const float* __restrict__ teacher,
                                            unsigned short* __restrict__ P,
                                            unsigned char* __restrict__ QT,
                                            float* __restrict__ qpart,
                                            float* __restrict__ rowexp,
                                            float* __restrict__ possum,
                                            float* __restrict__ cntw,
                                            float* __restrict__ dtot) {
  __shared__ float rnt[16];
  __shared__ unsigned char QL[16 * 897];  // odd pitch: bank-spread col gathers
  const int t = threadIdx.x, wave = t >> 6, lane = t & 63;
  const int r0 = (int)blockIdx.x * 16;

#pragma unroll
  for (int rr = 0; rr < 4; ++rr) {
    const int rl = wave * 4 + rr, r = r0 + rl;
    float ss = 0.f;
#pragma unroll
    for (int i = 0; i < 3; ++i) {
      const float4 v = *(const float4*)&teacher[(size_t)r * 768 + i * 256 + lane * 4];
      ss += v.x * v.x + v.y * v.y + v.z * v.z + v.w * v.w;
    }
    const float2 lv = *(const float2*)&logits[(size_t)r * 128 + lane * 2];
    float ssl = lv.x * lv.x + lv.y * lv.y;
    float qv = fabsf(fabsf(lv.x) - 1.f) + fabsf(fabsf(lv.y) - 1.f);
#pragma unroll
    for (int off = 1; off < 64; off <<= 1) {
      ss += __shfl_xor(ss, off, 64);
      ssl += __shfl_xor(ssl, off, 64);
      qv += __shfl_xor(qv, off, 64);
    }
    const float rnl = 1.f / fmaxf(sqrtf(ssl), 1e-12f);
    const unsigned int pk = (unsigned int)f2bf(lv.x * rnl) |
                            ((unsigned int)f2bf(lv.y * rnl) << 16);
    *(unsigned int*)&P[(size_t)r * 128 + lane * 2] = pk;
    if (lane == 0) {
      rnt[rl] = 11.313708498984761f / fmaxf(sqrtf(ss), 1e-12f);  // sqrt128/||t||
      qpart[r] = qv;
    }
  }
  if (t < 16) { rowexp[r0 + t] = 0.f; possum[r0 + t] = 0.f; cntw[r0 + t] = 0.f; }
  if (blockIdx.x == 0 && t == 0) *dtot = 0.f;
  __syncthreads();

  // B: task = (row, 16-col block). 16 rows x 56 blocks = 896 tasks.
#pragma unroll
  for (int it = 0; it < 4; ++it) {
    const int task = it * 256 + t;
    if (task < 896) {
      const int r = task / 56, cb = task % 56;
      const int r_g = r0 + r;
      unsigned char* dst = &QL[r * 897 + cb * 16];
      if (cb < 8) {  // hash cols 0..127: exact +-1.0 e4m3
        const float4 v0 = *(const float4*)&hash[(size_t)r_g * 128 + cb * 16];
        const float4 v1 = *(const float4*)&hash[(size_t)r_g * 128 + cb * 16 + 4];
        const float4 v2 = *(const float4*)&hash[(size_t)r_g * 128 + cb * 16 + 8];
        const float4 v3 = *(const float4*)&hash[(size_t)r_g * 128 + cb * 16 + 12];
        const float vv[16] = {v0.x, v0.y, v0.z, v0.w, v1.x, v1.y, v1.z, v1.w,
                              v2.x, v2.y, v2.z, v2.w, v3.x, v3.y, v3.z, v3.w};
#pragma unroll
        for (int k = 0; k < 16; ++k) dst[k] = vv[k] >= 0.f ? 0x38 : 0xB8;
      } else {  // teacher cols: * sqrt(128)/||t||, fp8 e4m3
        const float sc = rnt[r];
        const int c0 = cb * 16 - 128;
        const float4 v0 = *(const float4*)&teacher[(size_t)r_g * 768 + c0];
        const float4 v1 = *(const float4*)&teacher[(size_t)r_g * 768 + c0 + 4];
        const float4 v2 = *(const float4*)&teacher[(size_t)r_g * 768 + c0 + 8];
        const float4 v3 = *(const float4*)&teacher[(size_t)r_g * 768 + c0 + 12];
        const float vv[16] = {v0.x, v0.y, v0.z, v0.w, v1.x, v1.y, v1.z, v1.w,
                              v2.x, v2.y, v2.z, v2.w, v3.x, v3.y, v3.z, v3.w};
#pragma unroll
        for (int k = 0; k < 16; ++k) {
          const int p8 = __builtin_amdgcn_cvt_pk_fp8_f32(vv[k] * sc, vv[k] * sc,
                                                         0, false);
          dst[k] = (unsigned char)(p8 & 0xFF);
        }
      }
    }
  }
  __syncthreads();

  // C: transpose-write. Thread owns column c: gather 16 rows, one 16B store.
#pragma unroll
  for (int i = 0; i < 4; ++i) {
    const int c = t + 256 * i;
    if (c < 896) {
      unsigned char buf[16];
#pragma unroll
      for (int j = 0; j < 16; ++j) buf[j] = QL[j * 897 + c];
      *(uint4*)&QT[(size_t)c * 4096 + r0] = *(uint4*)buf;
    }
  }
}

// Stage 128 rows x 128 BYTES from gA (and gB if offdiag) into LDS bytes
// [0..16K) / [16K..32K). 16B-slot p of row holds global chunk p^(row&7).
#define STAGE_GEN(GA, GB, PITCH)                                               \
  {                                                                            \
    _Pragma("unroll") for (int it = 0; it < 4; ++it) {                         \
      const int task = it * 256 + t;                                           \
      const int row = task >> 3;                                               \
      const int c16 = (task & 7) ^ (row & 7);                                  \
      const unsigned char* gpA = (GA) + (size_t)row * (PITCH) + c16 * 16;      \
      __builtin_amdgcn_global_load_lds(                                        \
          (const __attribute__((address_space(1))) void*)gpA,                  \
          (__attribute__((address_space(3))) void*)                            \
              &SB[it * 4096 + wave * 1024],                                    \
          16, 0, 0);                                                           \
      if (offdiag) {                                                           \
        const unsigned char* gpB = (GB) + (size_t)row * (PITCH) + c16 * 16;    \
        __builtin_amdgcn_global_load_lds(                                      \
            (const __attribute__((address_space(1))) void*)gpB,                \
            (__attribute__((address_space(3))) void*)                         \
                &SB[16384 + it * 4096 + wave * 1024],                          \
            16, 0, 0);                                                         \
      }                                                                        \
    }                                                                          \
  }

// bf16 chunk (64 cols = 2 ksteps), 16 MFMA each. Wave (wy,wx) owns 64x64 quad.
#define MFMA_B()                                                               \
  {                                                                            \
    _Pragma("unroll") for (int ks = 0; ks < 2; ++ks) {                         \
      const int ph = ((ks * 4 + qd) ^ (l15 & 7)) * 16;                         \
      bf16x8 af[4], bfr[4];                                                    \
      _Pragma("unroll") for (int rt = 0; rt < 4; ++rt)                         \
          af[rt] = *(const bf16x8*)&SB[(wy * 64 + rt * 16 + l15) * 128 + ph];  \
      _Pragma("unroll") for (int ct = 0; ct < 4; ++ct)                         \
          bfr[ct] = *(const bf16x8*)&SB[boffB +                                \
                                        (wx * 64 + ct * 16 + l15) * 128 + ph]; \
      _Pragma("unroll") for (int rt = 0; rt < 4; ++rt)                         \
          _Pragma("unroll") for (int ct = 0; ct < 4; ++ct) acc[rt][ct] =       \
          __builtin_amdgcn_mfma_f32_16x16x32_bf16(af[rt], bfr[ct],             \
                                                  acc[rt][ct], 0, 0, 0);       \
    }                                                                          \
  }

// fp8 chunk (128 cols = 4 ksteps), 16 MFMA each; 8B frags.
#define MFMA_Q()                                                               \
  {                                                                            \
    _Pragma("unroll") for (int ks = 0; ks < 4; ++ks) {                         \
      const int g0 = ks * 4 + qd;                                              \
      const int ph = ((g0 >> 1) ^ (l15 & 7)) * 16 + (g0 & 1) * 8;              \
      long af[4], bfr[4];                                                      \
      _Pragma("unroll") for (int rt = 0; rt < 4; ++rt)                         \
          af[rt] = *(const long*)&SB[(wy * 64 + rt * 16 + l15) * 128 + ph];    \
      _Pragma("unroll") for (int ct = 0; ct < 4; ++ct)                         \
          bfr[ct] = *(const long*)&SB[boffB +                                  \
                                      (wx * 64 + ct * 16 + l15) * 128 + ph];   \
      _Pragma("unroll") for (int rt = 0; rt < 4; ++rt)                         \
          _Pragma("unroll") for (int ct = 0; ct < 4; ++ct) acc[rt][ct] =       \
          __builtin_amdgcn_mfma_f32_16x16x32_fp8_fp8(af[rt], bfr[ct],          \
                                                     acc[rt][ct], 0, 0, 0);    \
    }                                                                          \
  }

__global__ __launch_bounds__(256, 4) void mega(const unsigned short* __restrict__ P,
                                               const unsigned char* __restrict__ QT,
                                               const void* __restrict__ mask,
                                               float* __restrict__ rowexp,
                                               float* __restrict__ possum,
                                               float* __restrict__ cntw,
                                               float* __restrict__ Cpart) {
  __shared__ __align__(16) unsigned char SB[32768];  // A @0, B @16K (single buf)
  __shared__ float redrow[128][2];

  const int t = threadIdx.x;
  const int wave = t >> 6, lane = t & 63;
  const int qd = lane >> 4, l15 = lane & 15;
  const int wy = wave >> 1, wx = wave & 1;
  const int b = (int)blockIdx.x;

  f32x4 acc[4][4];
#pragma unroll
  for (int rt = 0; rt < 4; ++rt)
#pragma unroll
    for (int ct = 0; ct < 4; ++ct) acc[rt][ct] = {0.f, 0.f, 0.f, 0.f};

  if (b < 112) {
    // ---- G-role: partial C = Q^T Q tile (I,J), K-slice ksl of 4 (K=1024).
    // 8 chunks, single-buffered: STAGE; bar; MFMA; bar.
    const int tile = b >> 2, ksl = b & 3;
    int I = 0, rem = tile;
    while (rem >= 7 - I) { rem -= 7 - I; ++I; }
    const int J = I + rem;
    const bool offdiag = (I != J);
    const int boffB = offdiag ? 16384 : 0;
    const unsigned char* QA = QT + (size_t)I * 128 * 4096 + ksl * 1024;
    const unsigned char* QB = QT + (size_t)J * 128 * 4096 + ksl * 1024;

    for (int kc = 0; kc < 8; ++kc) {
      STAGE_GEN(QA + kc * 128, QB + kc * 128, 4096);
      __syncthreads();   // chunk staged (vmcnt drain)
      MFMA_Q();
      __syncthreads();   // all ds_reads done; slab reusable
    }
    // private coalesced partial store: thread-major, 256B/thread
    float* Ct = Cpart + ((size_t)(tile * 4 + ksl)) * 16384 + t * 64;
#pragma unroll
    for (int rt = 0; rt < 4; ++rt)
#pragma unroll
      for (int ct = 0; ct < 4; ++ct)
        *(f32x4*)&Ct[(rt * 4 + ct) * 4] = acc[rt][ct];
  } else {
    // ---- S-role: ln gram (bf16), FULL-square 128x128 tile + mask epilogue --
    const int bb = b - 112;
    const int l = (bb & 7) * 128 + (bb >> 3);  // XCD swizzle (1024 = 8*128)
    const int bi = l >> 5, bj = l & 31;
    const int ti = bi * 128, tj = bj * 128;
    const bool offdiag = (bi != bj);           // diag tile: B = A (boffB 0)
    const int boffB = offdiag ? 16384 : 0;
    const bool is_byte = ((const unsigned char*)mask)[4097] != 0;

    const unsigned char* Pa = (const unsigned char*)(P + (size_t)ti * 128);
    const unsigned char* Pb = (const unsigned char*)(P + (size_t)tj * 128);

    STAGE_GEN(Pa, Pb, 256);
    __syncthreads();
    MFMA_B();
    __syncthreads();
    STAGE_GEN(Pa + 128, Pb + 128, 256);
    __syncthreads();
    MFMA_B();
    __syncthreads();   // reads done; slab free for mask

    // issue mask prefetch into freed slab; RTT hides under the exp-sum pass
    if (is_byte) {
      const unsigned char* m8d = (const unsigned char*)mask + (size_t)ti * 4096 + tj;
#pragma unroll
      for (int it = 0; it < 4; ++it) {
        const int task = it * 256 + t;
        const int row = task >> 3, seg = task & 7;
        __builtin_amdgcn_global_load_lds(
            (const __attribute__((address_space(1))) void*)
                (m8d + (size_t)row * 4096 + seg * 16),
            (__attribute__((address_space(3))) void*)&SB[it * 4096 + wave * 1024],
            16, 0, 0);
      }
    }

    // scale sims in place; pass 1: exp row-sums (mask-independent)
#pragma unroll
    for (int rt = 0; rt < 4; ++rt)
#pragma unroll
      for (int ct = 0; ct < 4; ++ct) acc[rt][ct] *= 5.0f;  // /TEMPERATURE

#pragma unroll
    for (int rt = 0; rt < 4; ++rt) {
#pragma unroll
      for (int r = 0; r < 4; ++r) {
        const int mrow = wy * 64 + rt * 16 + qd * 4 + r;  // C/D: row=qd*4+reg
        const int m = ti + mrow;
        float se = 0.f;
#pragma unroll
        for (int ct = 0; ct < 4; ++ct) {
          const int n = tj + wx * 64 + ct * 16 + l15;     // C/D: col=lane&15
          const float e = __expf(acc[rt][ct][r]);
          if (m != n) se += e;                            // diag excluded
        }
#pragma unroll
        for (int off = 1; off < 16; off <<= 1) se += __shfl_xor(se, off, 64);
        if (l15 == 0) redrow[mrow][wx] = se;
      }
    }
    __syncthreads();   // drains mask loads; redrow visible

    if (!is_byte) {
      const unsigned int* m32 = (const unsigned int*)mask;
#pragma unroll
      for (int it = 0; it < 16; ++it) {
        const int task = it * 256 + t;
        const int row = task >> 5, seg = task & 31;
        const uint4 v = *(const uint4*)&m32[(size_t)(ti + row) * 4096 + tj + seg * 4];
        uchar4 pk;
        pk.x = v.x ? 1 : 0; pk.y = v.y ? 1 : 0;
        pk.z = v.z ? 1 : 0; pk.w = v.w ? 1 : 0;
        *(uchar4*)&SB[row * 128 + seg * 4] = pk;
      }
      __syncthreads();
    }

    if (t < 128) atomAddF(&rowexp[ti + t], redrow[t][0] + redrow[t][1]);

    // pass 2: sparse positive atomics (sim values still in acc, scaled)
#pragma unroll
    for (int rt = 0; rt < 4; ++rt) {
#pragma unroll
      for (int r = 0; r < 4; ++r) {
        const int mrow = wy * 64 + rt * 16 + qd * 4 + r;
        const int m = ti + mrow;
#pragma unroll
        for (int ct = 0; ct < 4; ++ct) {
          const int ncol = wx * 64 + ct * 16 + l15;
          if (SB[mrow * 128 + ncol]) {
            atomAddF(&possum[m], acc[rt][ct][r]);
            atomAddF(&cntw[m], 1.0f);
          }
        }
      }
    }
  }
}

// gsq: sum the 4 K-slice partials per element, square, sign-weight -> dtot.
// 28 tiles x 16384 elems = 458752; 448 blocks x 256 thr x 4 elems.
__global__ __launch_bounds__(256) void gsq(const float* __restrict__ Cpart,
                                           float* __restrict__ dtot) {
  const int t = threadIdx.x;
  const int wave = t >> 6, lane = t & 63;
  float s = 0.f;
  for (int e = (int)blockIdx.x * 256 + t; e < 458752; e += 448 * 256) {
    const int tile = e >> 14, idx = e & 16383;
    int I = 0, rem = tile;
    while (rem >= 7 - I) { rem -= 7 - I; ++I; }
    const int J = I + rem;
    float v = 0.f;
#pragma unroll
    for (int k = 0; k < 4; ++k)
      v += Cpart[((size_t)(tile * 4 + k)) * 16384 + idx];
    const float w = (I == J ? 1.f : 2.f) * (((I == 0) == (J == 0)) ? 1.f : -1.f);
    s += w * v * v;
  }
#pragma unroll
  for (int off = 1; off < 64; off <<= 1) s += __shfl_xor(s, off, 64);
  __shared__ float sw[4];
  if (lane == 0) sw[wave] = s;
  __syncthreads();
  if (t == 0) atomAddF(dtot, sw[0] + sw[1] + sw[2] + sw[3]);
}

__global__ __launch_bounds__(1024) void finalize(const float* __restrict__ rowexp,
                                                 const float* __restrict__ possum,
                                                 const float* __restrict__ cnt,
                                                 const float* __restrict__ qpart,
                                                 const float* __restrict__ dtot,
                                                 float* __restrict__ out) {
  const int t = threadIdx.x;
  const int wave = t >> 6, lane = t & 63;
  float c = 0.f, q = 0.f;
  for (int m = t; m < 4096; m += 1024) {
    c += logf(rowexp[m]) - possum[m] / fmaxf(cnt[m], 1.0f);
    q += qpart[m];
  }
#pragma unroll
  for (int off = 1; off < 64; off <<= 1) {
    c += __shfl_xor(c, off, 64);
    q += __shfl_xor(q, off, 64);
  }
  __shared__ float sc[16], sq[16];
  if (lane == 0) { sc[wave] = c; sq[wave] = q; }
  __syncthreads();
  if (t == 0) {
    float C = 0.f, Q = 0.f;
    for (int i = 0; i < 16; ++i) { C += sc[i]; Q += sq[i]; }
    // dtot = 16384 * B^2 * loss_distill -> 0.5 * dtot / (4096^2 * 16384)
    out[0] = C * (1.0f / 4096.0f) + 0.5f * (dtot[0] * 3.6379788e-12f) +
             0.01f * (Q * (1.0f / 524288.0f));
  }
}

extern "C" void kernel_launch(void* const* d_in, const int* in_sizes, int n_in,
                              void* d_out, int out_size, void* d_ws, size_t ws_size,
                              hipStream_t stream) {
  const float* logits = (const float*)d_in[0];
  const float* hash = (const float*)d_in[1];
  const float* teacher = (const float*)d_in[2];
  const void* mask = d_in[3];
  float* out = (float*)d_out;

  char* ws = (char*)d_ws;
  float* rowexp = (float*)(ws + 0);
  float* possum = (float*)(ws + 16384);
  float* cntw = (float*)(ws + 32768);
  float* qpart = (float*)(ws + 49152);
  float* dtot = (float*)(ws + 65536);
  unsigned short* P = (unsigned short*)(ws + 98304);           // 4096x128 bf16 = 1 MB
  unsigned char* QT = (unsigned char*)(ws + 98304 + 1048576);  // 896x4096 fp8 = 3.5 MB
  float* Cpart = (float*)(ws + 98304 + 1048576 + 3670016);     // 28x4x16384 f32 = 7 MB

  prep<<<256, 256, 0, stream>>>(logits, hash, teacher, P, QT, qpart, rowexp,
                                possum, cntw, dtot);
  mega<<<1136, 256, 0, stream>>>(P, QT, mask, rowexp, possum, cntw, Cpart);
  gsq<<<448, 256, 0, stream>>>(Cpart, dtot);
  finalize<<<1, 1024, 0, stream>>>(rowexp, possum, cntw, qpart, dtot, out);
}

// Round 4
// 151.880 us; speedup vs baseline: 1.0529x; 1.0529x over previous
//
#include <hip/hip_runtime.h>

// HashLoss: contrastive (logsumexp over ln@ln^T/0.2) + 0.5*MSE(H@H^T/128, Tn@Tn^T)
//         + 0.01*mean||logits|-1|
// B=4096. R16: overhead-reduction round. Cross-round bookkeeping: non-mega time
// is ~99-113us while the non-mega kernels compute ~15us -> per-dispatch fixed
// cost (~7us) + per-MB-ws cost (~1us/MB) dominate. So: (1) 4->3 dispatches
// (gsq+finalize fused into `reduce` w/ last-block-done counter; completion path
// is all-atomic: partials via unsafeAtomicAdd, final read via
// unsafeAtomicAdd(p,0.f) - no plain-load coherence hazard; fences once/block,
// not in hot loops). (2) ws 11.7->6.65MB: Cpart(7MB) -> Cbuf(1.75MB) with
// COALESCED HW-fadd atomics from G-blocks (lane-major layout: wave's 64 atomics
// = 4 cachelines; R13's regression was CAS-loop atomics, not traffic).
// (3) mega reverted to R14's best structure (2-deep dbuf, 43.6us), epilogue
// swapped. (4) prep 512 blocks x 8 rows (halves serial row chain).

typedef __bf16 bf16x8 __attribute__((ext_vector_type(8)));
typedef float f32x4 __attribute__((ext_vector_type(4)));

__device__ __forceinline__ unsigned short f2bf(float f) {
  union { float f; unsigned int u; } v; v.f = f;
  unsigned int u = v.u;
  return (unsigned short)((u + 0x7FFFu + ((u >> 16) & 1u)) >> 16);  // RNE
}

__device__ __forceinline__ void atomAddF(float* p, float v) {
  unsafeAtomicAdd(p, v);  // HW f32 fadd (fire-and-forget), not CAS loop
}

// ---- prep: 512 blocks x 256 threads, 8 rows each.
// A: norms -> P bf16, qpart, rnt (wave per row, 2 serial rows/wave).
// B: quantize 8x896 fp8 slab into QL (odd pitch 897).
// C: 896 column-gathers -> 8B stores to QT[c][r0..r0+8).
// Also zeroes Cbuf (1.75MB/512 blocks = 224 f32x4 each) + accs/counter.
__global__ __launch_bounds__(256) void prep(const float* __restrict__ logits,
                                            const float* __restrict__ hash,
                                            const float* __restrict__ teacher,
                                            unsigned short* __restrict__ P,
                                            unsigned char* __restrict__ QT,
                                            float* __restrict__ qpart,
                                            float* __restrict__ rowexp,
                                            float* __restrict__ possum,
                                            float* __restrict__ cntw,
                                            float* __restrict__ accs,
                                            float* __restrict__ Cbuf) {
  __shared__ float rnt[8];
  __shared__ unsigned char QL[8 * 897];  // odd pitch: bank-spread col gathers
  const int t = threadIdx.x, wave = t >> 6, lane = t & 63;
  const int r0 = (int)blockIdx.x * 8;

  // zero Cbuf slice: 512 blocks x 224 f32x4 = 114688 f32x4 = 28*16384 floats
  for (int i = t; i < 224; i += 256)
    *(f32x4*)&Cbuf[((size_t)blockIdx.x * 224 + i) * 4] = (f32x4){0.f, 0.f, 0.f, 0.f};
  if (blockIdx.x == 0) {
    if (t < 4) accs[t] = 0.f;            // [0]=C,[1]=Q,[2]=D
    if (t == 4) *(int*)&accs[4] = 0;     // completion counter
  }

#pragma unroll
  for (int rr = 0; rr < 2; ++rr) {
    const int rl = wave * 2 + rr, r = r0 + rl;
    float ss = 0.f;
#pragma unroll
    for (int i = 0; i < 3; ++i) {
      const float4 v = *(const float4*)&teacher[(size_t)r * 768 + i * 256 + lane * 4];
      ss += v.x * v.x + v.y * v.y + v.z * v.z + v.w * v.w;
    }
    const float2 lv = *(const float2*)&logits[(size_t)r * 128 + lane * 2];
    float ssl = lv.x * lv.x + lv.y * lv.y;
    float qv = fabsf(fabsf(lv.x) - 1.f) + fabsf(fabsf(lv.y) - 1.f);
#pragma unroll
    for (int off = 1; off < 64; off <<= 1) {
      ss += __shfl_xor(ss, off, 64);
      ssl += __shfl_xor(ssl, off, 64);
      qv += __shfl_xor(qv, off, 64);
    }
    const float rnl = 1.f / fmaxf(sqrtf(ssl), 1e-12f);
    const unsigned int pk = (unsigned int)f2bf(lv.x * rnl) |
                            ((unsigned int)f2bf(lv.y * rnl) << 16);
    *(unsigned int*)&P[(size_t)r * 128 + lane * 2] = pk;
    if (lane == 0) {
      rnt[rl] = 11.313708498984761f / fmaxf(sqrtf(ss), 1e-12f);  // sqrt128/||t||
      qpart[r] = qv;
    }
  }
  if (t < 8) { rowexp[r0 + t] = 0.f; possum[r0 + t] = 0.f; cntw[r0 + t] = 0.f; }
  __syncthreads();

  // B: task = (row, 16-col block). 8 rows x 56 blocks = 448 tasks.
#pragma unroll
  for (int it = 0; it < 2; ++it) {
    const int task = it * 256 + t;
    if (task < 448) {
      const int r = task / 56, cb = task % 56;
      const int r_g = r0 + r;
      unsigned char* dst = &QL[r * 897 + cb * 16];
      if (cb < 8) {  // hash cols 0..127: exact +-1.0 e4m3
        const float4 v0 = *(const float4*)&hash[(size_t)r_g * 128 + cb * 16];
        const float4 v1 = *(const float4*)&hash[(size_t)r_g * 128 + cb * 16 + 4];
        const float4 v2 = *(const float4*)&hash[(size_t)r_g * 128 + cb * 16 + 8];
        const float4 v3 = *(const float4*)&hash[(size_t)r_g * 128 + cb * 16 + 12];
        const float vv[16] = {v0.x, v0.y, v0.z, v0.w, v1.x, v1.y, v1.z, v1.w,
                              v2.x, v2.y, v2.z, v2.w, v3.x, v3.y, v3.z, v3.w};
#pragma unroll
        for (int k = 0; k < 16; ++k) dst[k] = vv[k] >= 0.f ? 0x38 : 0xB8;
      } else {  // teacher cols: * sqrt(128)/||t||, fp8 e4m3
        const float sc = rnt[r];
        const int c0 = cb * 16 - 128;
        const float4 v0 = *(const float4*)&teacher[(size_t)r_g * 768 + c0];
        const float4 v1 = *(const float4*)&teacher[(size_t)r_g * 768 + c0 + 4];
        const float4 v2 = *(const float4*)&teacher[(size_t)r_g * 768 + c0 + 8];
        const float4 v3 = *(const float4*)&teacher[(size_t)r_g * 768 + c0 + 12];
        const float vv[16] = {v0.x, v0.y, v0.z, v0.w, v1.x, v1.y, v1.z, v1.w,
                              v2.x, v2.y, v2.z, v2.w, v3.x, v3.y, v3.z, v3.w};
#pragma unroll
        for (int k = 0; k < 16; ++k) {
          const int p8 = __builtin_amdgcn_cvt_pk_fp8_f32(vv[k] * sc, vv[k] * sc,
                                                         0, false);
          dst[k] = (unsigned char)(p8 & 0xFF);
        }
      }
    }
  }
  __syncthreads();

  // C: transpose-write. Thread owns column c: gather 8 rows, one 8B store.
#pragma unroll
  for (int i = 0; i < 4; ++i) {
    const int c = t + 256 * i;
    if (c < 896) {
      unsigned char buf[8];
#pragma unroll
      for (int j = 0; j < 8; ++j) buf[j] = QL[j * 897 + c];
      *(uint2*)&QT[(size_t)c * 4096 + r0] = *(uint2*)buf;
    }
  }
}

// Stage 128 rows x 128 BYTES from gA (and gB if offdiag) into LDS slab at BASE
// (A at BASE, B at BASE+16K). 16B-slot p of row holds global chunk p^(row&7).
#define STAGE_GEN(GA, GB, PITCH, BASE)                                         \
  {                                                                            \
    _Pragma("unroll") for (int it = 0; it < 4; ++it) {                         \
      const int task = it * 256 + t;                                           \
      const int row = task >> 3;                                               \
      const int c16 = (task & 7) ^ (row & 7);                                  \
      const unsigned char* gpA = (GA) + (size_t)row * (PITCH) + c16 * 16;      \
      __builtin_amdgcn_global_load_lds(                                        \
          (const __attribute__((address_space(1))) void*)gpA,                  \
          (__attribute__((address_space(3))) void*)                            \
              &SB[(BASE) + it * 4096 + wave * 1024],                           \
          16, 0, 0);                                                           \
      if (offdiag) {                                                           \
        const unsigned char* gpB = (GB) + (size_t)row * (PITCH) + c16 * 16;    \
        __builtin_amdgcn_global_load_lds(                                      \
            (const __attribute__((address_space(1))) void*)gpB,                \
            (__attribute__((address_space(3))) void*)                         \
                &SB[(BASE) + 16384 + it * 4096 + wave * 1024],                 \
            16, 0, 0);                                                         \
      }                                                                        \
    }                                                                          \
  }

// bf16 chunk (64 cols = 2 ksteps), 16 MFMA each. Wave (wy,wx) owns 64x64 quad.
#define MFMA_B(BASE)                                                           \
  {                                                                            \
    _Pragma("unroll") for (int ks = 0; ks < 2; ++ks) {                         \
      const int ph = ((ks * 4 + qd) ^ (l15 & 7)) * 16;                         \
      bf16x8 af[4], bfr[4];                                                    \
      _Pragma("unroll") for (int rt = 0; rt < 4; ++rt)                         \
          af[rt] = *(const bf16x8*)&SB[(BASE) +                                \
                                       (wy * 64 + rt * 16 + l15) * 128 + ph];  \
      _Pragma("unroll") for (int ct = 0; ct < 4; ++ct)                         \
          bfr[ct] = *(const bf16x8*)&SB[(BASE) + boffB +                       \
                                        (wx * 64 + ct * 16 + l15) * 128 + ph]; \
      _Pragma("unroll") for (int rt = 0; rt < 4; ++rt)                         \
          _Pragma("unroll") for (int ct = 0; ct < 4; ++ct) acc[rt][ct] =       \
          __builtin_amdgcn_mfma_f32_16x16x32_bf16(af[rt], bfr[ct],             \
                                                  acc[rt][ct], 0, 0, 0);       \
    }                                                                          \
  }

// fp8 chunk (128 cols = 4 ksteps), 16 MFMA each; 8B frags.
#define MFMA_Q(BASE)                                                           \
  {                                                                            \
    _Pragma("unroll") for (int ks = 0; ks < 4; ++ks) {                         \
      const int g0 = ks * 4 + qd;                                              \
      const int ph = ((g0 >> 1) ^ (l15 & 7)) * 16 + (g0 & 1) * 8;              \
      long af[4], bfr[4];                                                      \
      _Pragma("unroll") for (int rt = 0; rt < 4; ++rt)                         \
          af[rt] = *(const long*)&SB[(BASE) +                                  \
                                     (wy * 64 + rt * 16 + l15) * 128 + ph];    \
      _Pragma("unroll") for (int ct = 0; ct < 4; ++ct)                         \
          bfr[ct] = *(const long*)&SB[(BASE) + boffB +                         \
                                      (wx * 64 + ct * 16 + l15) * 128 + ph];   \
      _Pragma("unroll") for (int rt = 0; rt < 4; ++rt)                         \
          _Pragma("unroll") for (int ct = 0; ct < 4; ++ct) acc[rt][ct] =       \
          __builtin_amdgcn_mfma_f32_16x16x32_fp8_fp8(af[rt], bfr[ct],          \
                                                     acc[rt][ct], 0, 0, 0);    \
    }                                                                          \
  }

__global__ __launch_bounds__(256, 2) void mega(const unsigned short* __restrict__ P,
                                               const unsigned char* __restrict__ QT,
                                               const void* __restrict__ mask,
                                               float* __restrict__ rowexp,
                                               float* __restrict__ possum,
                                               float* __restrict__ cntw,
                                               float* __restrict__ Cbuf) {
  // 4 slabs of 16KB: A0@0 B0@16K A1@32K B1@48K (2-deep double buffer)
  __shared__ __align__(16) unsigned char SB[65536];
  __shared__ float redrow[128][2];

  const int t = threadIdx.x;
  const int wave = t >> 6, lane = t & 63;
  const int qd = lane >> 4, l15 = lane & 15;
  const int wy = wave >> 1, wx = wave & 1;
  const int b = (int)blockIdx.x;

  f32x4 acc[4][4];
#pragma unroll
  for (int rt = 0; rt < 4; ++rt)
#pragma unroll
    for (int ct = 0; ct < 4; ++ct) acc[rt][ct] = {0.f, 0.f, 0.f, 0.f};

  if (b < 112) {
    // ---- G-role: partial C = Q^T Q tile (I,J), K-slice ksl of 4 (K=1024).
    // 8 chunks, double-buffered: STAGE(next) || MFMA(cur), 1 barrier/chunk.
    const int tile = b >> 2, ksl = b & 3;
    int I = 0, rem = tile;
    while (rem >= 7 - I) { rem -= 7 - I; ++I; }
    const int J = I + rem;
    const bool offdiag = (I != J);
    const int boffB = offdiag ? 16384 : 0;
    const unsigned char* QA = QT + (size_t)I * 128 * 4096 + ksl * 1024;
    const unsigned char* QB = QT + (size_t)J * 128 * 4096 + ksl * 1024;

    STAGE_GEN(QA, QB, 4096, 0);
    __syncthreads();  // drains chunk0
    for (int kc = 0; kc < 8; ++kc) {
      const int cb = (kc & 1) * 32768;
      if (kc < 7) STAGE_GEN(QA + (kc + 1) * 128, QB + (kc + 1) * 128, 4096,
                            cb ^ 32768);
      MFMA_Q(cb);
      __syncthreads();  // implicit vmcnt(0): next chunk ready; cur slab free
    }
    // coalesced HW-fadd partial accumulate: lane-major layout, a wave's 64
    // atomics hit 64 consecutive floats (4 cachelines). Fragment->element map
    // within the tile is irrelevant (reduce only needs tile-level sign).
    float* Ct = Cbuf + (size_t)tile * 16384;
#pragma unroll
    for (int rt = 0; rt < 4; ++rt)
#pragma unroll
      for (int ct = 0; ct < 4; ++ct)
#pragma unroll
        for (int i = 0; i < 4; ++i)
          atomAddF(&Ct[(rt * 4 + ct) * 1024 + i * 256 + t], acc[rt][ct][i]);
  } else {
    // ---- S-role: ln gram (bf16), FULL-square 128x128 tile + mask epilogue --
    const int bb = b - 112;
    const int l = (bb & 7) * 128 + (bb >> 3);  // XCD swizzle (1024 = 8*128)
    const int bi = l >> 5, bj = l & 31;
    const int ti = bi * 128, tj = bj * 128;
    const bool offdiag = (bi != bj);           // diag tile: B = A (boffB 0)
    const int boffB = offdiag ? 16384 : 0;
    const bool is_byte = ((const unsigned char*)mask)[4097] != 0;

    const unsigned char* Pa = (const unsigned char*)(P + (size_t)ti * 128);
    const unsigned char* Pb = (const unsigned char*)(P + (size_t)tj * 128);

    STAGE_GEN(Pa, Pb, 256, 0);
    __syncthreads();                       // chunk0 ready
    STAGE_GEN(Pa + 128, Pb + 128, 256, 32768);
    MFMA_B(0);
    __syncthreads();                       // chunk1 ready; slab0/1 free
    if (is_byte) {
      // mask prefetch into freed slab0: RTT hides under 2nd MFMA phase
      const unsigned char* m8d = (const unsigned char*)mask + (size_t)ti * 4096 + tj;
#pragma unroll
      for (int it = 0; it < 4; ++it) {
        const int task = it * 256 + t;
        const int row = task >> 3, seg = task & 7;
        __builtin_amdgcn_global_load_lds(
            (const __attribute__((address_space(1))) void*)
                (m8d + (size_t)row * 4096 + seg * 16),
            (__attribute__((address_space(3))) void*)&SB[it * 4096 + wave * 1024],
            16, 0, 0);
      }
    }
    MFMA_B(32768);
    __syncthreads();                       // mask ready in SB[0..16K)
    if (!is_byte) {
      const unsigned int* m32 = (const unsigned int*)mask;
#pragma unroll
      for (int it = 0; it < 16; ++it) {
        const int task = it * 256 + t;
        const int row = task >> 5, seg = task & 31;
        const uint4 v = *(const uint4*)&m32[(size_t)(ti + row) * 4096 + tj + seg * 4];
        uchar4 pk;
        pk.x = v.x ? 1 : 0; pk.y = v.y ? 1 : 0;
        pk.z = v.z ? 1 : 0; pk.w = v.w ? 1 : 0;
        *(uchar4*)&SB[row * 128 + seg * 4] = pk;
      }
      __syncthreads();
    }

#pragma unroll
    for (int rt = 0; rt < 4; ++rt) {
#pragma unroll
      for (int r = 0; r < 4; ++r) {
        const int mrow = wy * 64 + rt * 16 + qd * 4 + r;  // C/D: row=qd*4+reg
        const int m = ti + mrow;
        float se = 0.f;
#pragma unroll
        for (int ct = 0; ct < 4; ++ct) {
          const int ncol = wx * 64 + ct * 16 + l15;       // C/D: col=lane&15
          const int n = tj + ncol;
          const float sim = acc[rt][ct][r] * 5.0f;        // /TEMPERATURE
          const float e = __expf(sim);
          if (m != n) se += e;                            // diag excluded
          if (SB[mrow * 128 + ncol]) {                    // sparse positives
            atomAddF(&possum[m], sim);
            atomAddF(&cntw[m], 1.0f);
          }
        }
#pragma unroll
        for (int off = 1; off < 16; off <<= 1) se += __shfl_xor(se, off, 64);
        if (l15 == 0) redrow[mrow][wx] = se;
      }
    }
    __syncthreads();
    if (t < 128) atomAddF(&rowexp[ti + t], redrow[t][0] + redrow[t][1]);
  }
}

// reduce = gsq + finalize fused. 64 blocks x 256 threads = 16384 threads.
// Each thread: 1 contrastive row + 7 f32x4 of Cbuf (7*16384 = 114688 = all).
// Block partials -> 3 HW-fadd atomics; last-block-done counter computes out.
// Completion path is all-atomic (reads via unsafeAtomicAdd(p,0.f)) - no
// plain-load-after-remote-atomic coherence hazard. Fences once per block.
__global__ __launch_bounds__(256) void reduce(const float* __restrict__ rowexp,
                                              const float* __restrict__ possum,
                                              const float* __restrict__ cnt,
                                              const float* __restrict__ qpart,
                                              const float* __restrict__ Cbuf,
                                              float* __restrict__ accs,
                                              float* __restrict__ out) {
  const int t = threadIdx.x;
  const int wave = t >> 6, lane = t & 63;
  const int g = (int)blockIdx.x * 256 + t;

  float c = 0.f, q = 0.f, d = 0.f;
  if (g < 4096) {
    c = logf(rowexp[g]) - possum[g] / fmaxf(cnt[g], 1.0f);
    q = qpart[g];
  }
#pragma unroll
  for (int k = 0; k < 7; ++k) {
    const int e4 = g + k * 16384;        // < 114688, exact cover
    const int tile = e4 >> 12;           // 4096 f32x4 per tile
    int I = 0, rem = tile;
    while (rem >= 7 - I) { rem -= 7 - I; ++I; }
    const int J = I + rem;
    const float w = (I == J ? 1.f : 2.f) * (((I == 0) == (J == 0)) ? 1.f : -1.f);
    const f32x4 v = *(const f32x4*)&Cbuf[(size_t)e4 * 4];
    d += w * (v[0] * v[0] + v[1] * v[1] + v[2] * v[2] + v[3] * v[3]);
  }
#pragma unroll
  for (int off = 1; off < 64; off <<= 1) {
    c += __shfl_xor(c, off, 64);
    q += __shfl_xor(q, off, 64);
    d += __shfl_xor(d, off, 64);
  }
  __shared__ float sc[4], sq[4], sd[4];
  if (lane == 0) { sc[wave] = c; sq[wave] = q; sd[wave] = d; }
  __syncthreads();
  if (t == 0) {
    atomAddF(&accs[0], sc[0] + sc[1] + sc[2] + sc[3]);
    atomAddF(&accs[1], sq[0] + sq[1] + sq[2] + sq[3]);
    atomAddF(&accs[2], sd[0] + sd[1] + sd[2] + sd[3]);
    __threadfence();  // order my atomics before the counter bump
    const int old = atomicAdd((int*)&accs[4], 1);
    if (old == 63) {  // last block: all partials are at the coherence point
      __threadfence();
      const float C = unsafeAtomicAdd(&accs[0], 0.f);
      const float Q = unsafeAtomicAdd(&accs[1], 0.f);
      const float D = unsafeAtomicAdd(&accs[2], 0.f);
      // D = 16384 * B^2 * loss_distill -> 0.5 * D / (4096^2 * 16384)
      out[0] = C * (1.0f / 4096.0f) + 0.5f * (D * 3.6379788e-12f) +
               0.01f * (Q * (1.0f / 524288.0f));
    }
  }
}

extern "C" void kernel_launch(void* const* d_in, const int* in_sizes, int n_in,
                              void* d_out, int out_size, void* d_ws, size_t ws_size,
                              hipStream_t stream) {
  const float* logits = (const float*)d_in[0];
  const float* hash = (const float*)d_in[1];
  const float* teacher = (const float*)d_in[2];
  const void* mask = d_in[3];
  float* out = (float*)d_out;

  char* ws = (char*)d_ws;
  float* rowexp = (float*)(ws + 0);
  float* possum = (float*)(ws + 16384);
  float* cntw = (float*)(ws + 32768);
  float* qpart = (float*)(ws + 49152);
  float* accs = (float*)(ws + 65536);                          // 4 f32 + int counter
  unsigned short* P = (unsigned short*)(ws + 98304);           // 4096x128 bf16 = 1 MB
  unsigned char* QT = (unsigned char*)(ws + 98304 + 1048576);  // 896x4096 fp8 = 3.5 MB
  float* Cbuf = (float*)(ws + 98304 + 1048576 + 3670016);      // 28x16384 f32 = 1.75 MB

  prep<<<512, 256, 0, stream>>>(logits, hash, teacher, P, QT, qpart, rowexp,
                                possum, cntw, accs, Cbuf);
  mega<<<1136, 256, 0, stream>>>(P, QT, mask, rowexp, possum, cntw, Cbuf);
  reduce<<<64, 256, 0, stream>>>(rowexp, possum, cntw, qpart, Cbuf, accs, out);
}